// Round 3
// baseline (345.901 us; speedup 1.0000x reference)
//
#include <hip/hip_runtime.h>
#include <hip/hip_bf16.h>
#include <stdint.h>

typedef __bf16 v8bf __attribute__((ext_vector_type(8)));
typedef float f32x4 __attribute__((ext_vector_type(4)));

__device__ __forceinline__ void gload_lds16(const void* g, void* l) {
    __builtin_amdgcn_global_load_lds(
        (const __attribute__((address_space(1))) void*)g,
        (__attribute__((address_space(3))) void*)l, 16, 0, 0);
}

__device__ __forceinline__ unsigned short f2bf(float f) {
    __hip_bfloat16 h = __float2bfloat16(f);
    return __builtin_bit_cast(unsigned short, h);
}

// ---- conversion kernels -------------------------------------------------
// xc = concat(x, c) along N axis, as bf16: [B=8][2048][512]
// total 8,388,608 elements = 2,097,152 float4 groups -> grid 8192 x 256
__global__ __launch_bounds__(256) void cvt_xc(const float* __restrict__ x,
                                              const float* __restrict__ c,
                                              __hip_bfloat16* __restrict__ xc) {
    int i = blockIdx.x * 256 + threadIdx.x;       // float4 index
    long e = (long)i * 4;
    int b = (int)(e >> 20);                       // 2048*512 = 1<<20
    int rem = (int)(e & ((1 << 20) - 1));
    int r = rem >> 9;
    int col = rem & 511;
    const float* src = (r < 1024) ? (x + ((long)b << 19) + (long)r * 512 + col)
                                  : (c + ((long)b << 19) + (long)(r - 1024) * 512 + col);
    float4 v = *(const float4*)src;
    ushort4 o;
    o.x = f2bf(v.x); o.y = f2bf(v.y); o.z = f2bf(v.z); o.w = f2bf(v.w);
    ((ushort4*)xc)[i] = o;
}

__global__ __launch_bounds__(256) void cvt_w(const float* __restrict__ q,
                                             const float* __restrict__ k,
                                             const float* __restrict__ v,
                                             const float* __restrict__ p,
                                             __hip_bfloat16* __restrict__ out) {
    int i = blockIdx.x * 256 + threadIdx.x;       // float4 index, 262,144 total
    int e = i * 4;
    int w = e >> 18;                              // 512*512 = 1<<18
    int off = e & ((1 << 18) - 1);
    const float* src = (w == 0 ? q : w == 1 ? k : w == 2 ? v : p) + off;
    float4 val = *(const float4*)src;
    ushort4 o;
    o.x = f2bf(val.x); o.y = f2bf(val.y); o.z = f2bf(val.z); o.w = f2bf(val.w);
    ((ushort4*)out)[i] = o;
}

// ---- GEMM: C[m,n] = sum_k A[m,k] * B[n,k]   (A: mapped rows of [.,512], B: [512][512])
// MODE 0: bf16 head-split out[((b*8+h)*seq + s)*64 + dh]
// MODE 1: bf16 transposed  out[((b*8+h)*64 + dh)*seq + s]   (V^T, seq=2048)
// MODE 2: fp32 plain       out[m*512 + n]
template <int MODE>
__global__ __launch_bounds__(256) void gemm_bt(const __hip_bfloat16* __restrict__ A,
                                               const __hip_bfloat16* __restrict__ Bw,
                                               void* __restrict__ outp,
                                               int row_div, int row_stride, int seq) {
    __shared__ __hip_bfloat16 As[128 * 32];
    __shared__ __hip_bfloat16 Bs[128 * 32];
    const int tid = threadIdx.x;
    const int wave = tid >> 6, lane = tid & 63;
    const int m0 = blockIdx.x * 128, n0 = blockIdx.y * 128;

    // staging addresses (row part constant over k-loop)
    const int la = lane >> 2;            // row within 16-row chunk
    const int kc = (lane & 3) * 8;       // k element offset within 32-wide tile
    const int ra0 = m0 + wave * 16 + la;
    const int ra1 = m0 + (wave + 4) * 16 + la;
    const long ga0 = (long)((ra0 / row_div) * row_stride + (ra0 % row_div)) * 512 + kc;
    const long ga1 = (long)((ra1 / row_div) * row_stride + (ra1 % row_div)) * 512 + kc;
    const long gb0 = (long)(n0 + wave * 16 + la) * 512 + kc;
    const long gb1 = (long)(n0 + (wave + 4) * 16 + la) * 512 + kc;

    f32x4 acc[4][4] = {};
    const int mw = (wave & 1) * 64, nw = (wave >> 1) * 64;
    const int lrow = lane & 15, lk = (lane >> 4) * 8;

    for (int k0 = 0; k0 < 512; k0 += 32) {
        gload_lds16(A + ga0 + k0, &As[wave * 512]);
        gload_lds16(A + ga1 + k0, &As[(wave + 4) * 512]);
        gload_lds16(Bw + gb0 + k0, &Bs[wave * 512]);
        gload_lds16(Bw + gb1 + k0, &Bs[(wave + 4) * 512]);
        __syncthreads();
        v8bf a[4], b[4];
#pragma unroll
        for (int i = 0; i < 4; i++) {
            a[i] = *(const v8bf*)&As[(mw + i * 16 + lrow) * 32 + lk];
            b[i] = *(const v8bf*)&Bs[(nw + i * 16 + lrow) * 32 + lk];
        }
#pragma unroll
        for (int mi = 0; mi < 4; mi++)
#pragma unroll
            for (int ni = 0; ni < 4; ni++)
                acc[mi][ni] = __builtin_amdgcn_mfma_f32_16x16x32_bf16(a[mi], b[ni], acc[mi][ni], 0, 0, 0);
        __syncthreads();
    }

    const int lq = lane >> 4;
#pragma unroll
    for (int mi = 0; mi < 4; mi++) {
#pragma unroll
        for (int ni = 0; ni < 4; ni++) {
#pragma unroll
            for (int r = 0; r < 4; r++) {
                int grow = m0 + mw + mi * 16 + lq * 4 + r;
                int gcol = n0 + nw + ni * 16 + lrow;
                float val = acc[mi][ni][r];
                if (MODE == 2) {
                    ((float*)outp)[(long)grow * 512 + gcol] = val;
                } else {
                    int b_ = grow / seq, s = grow % seq;
                    int h = gcol >> 6, dh = gcol & 63;
                    long idx;
                    if (MODE == 0) idx = ((long)(b_ * 8 + h) * seq + s) * 64 + dh;
                    else           idx = ((long)(b_ * 8 + h) * 64 + dh) * (long)seq + s;
                    ((__hip_bfloat16*)outp)[idx] = __float2bfloat16(val);
                }
            }
        }
    }
}

// ---- flash attention ----------------------------------------------------
// grid: (16 q-tiles, 64 b*h); block 256 = 4 waves; q-tile 64, k-tile 64
// mask arrives as int32 (harness uploads integer/bool inputs as int32)
__global__ __launch_bounds__(256) void flash(const __hip_bfloat16* __restrict__ Q,
                                             const __hip_bfloat16* __restrict__ K,
                                             const __hip_bfloat16* __restrict__ Vt,
                                             const int* __restrict__ mask,
                                             __hip_bfloat16* __restrict__ Y) {
    constexpr int LDT = 72;  // padded stride: breaks 16-way bank conflict on b128 frag reads
    __shared__ __hip_bfloat16 Qs[64 * LDT], Ks[64 * LDT], Vts[64 * LDT];
    __shared__ __hip_bfloat16 Ps[4][16 * LDT];
    __shared__ uint8_t Ms[64 * 64];

    const int qt = blockIdx.x, bh = blockIdx.y;
    const int b = bh >> 3, h = bh & 7;
    const int tid = threadIdx.x, wave = tid >> 6, lane = tid & 63;
    const __hip_bfloat16* Qp = Q + ((long)bh * 1024 + qt * 64) * 64;
    const __hip_bfloat16* Kp = K + (long)bh * 2048 * 64;
    const __hip_bfloat16* Vp = Vt + (long)bh * 64 * 2048;
    const int* Mp = mask + (long)b * 1024 * 2048 + (long)qt * 64 * 2048;

    {   // load Q tile [64 q][64 dh], padded
        const uint4* src = (const uint4*)Qp;
#pragma unroll
        for (int i = 0; i < 2; i++) {
            int u = tid + i * 256, r = u >> 3, part = u & 7;
            *(uint4*)&Qs[r * LDT + part * 8] = src[u];
        }
    }

    float mrow[4], lsum[4];
    f32x4 Oacc[4] = {};
#pragma unroll
    for (int r = 0; r < 4; r++) { mrow[r] = -3e38f; lsum[r] = 0.f; }

    const int lcol = lane & 15, lq = lane >> 4;

    for (int kt = 0; kt < 32; kt++) {
        {   // stage K tile [64 key][64 dh]
            const uint4* src = (const uint4*)(Kp + kt * 64 * 64);
#pragma unroll
            for (int i = 0; i < 2; i++) {
                int u = tid + i * 256, r = u >> 3, part = u & 7;
                *(uint4*)&Ks[r * LDT + part * 8] = src[u];
            }
            // stage V^T tile [64 dh][64 key]
#pragma unroll
            for (int i = 0; i < 2; i++) {
                int u = tid + i * 256, dh = u >> 3, part = u & 7;
                *(uint4*)&Vts[dh * LDT + part * 8] = *(const uint4*)(Vp + (long)dh * 2048 + kt * 64 + part * 8);
            }
            // stage mask tile [64 q][64 key]: int32 -> byte
#pragma unroll
            for (int i = 0; i < 4; i++) {
                int u = tid + i * 256;           // [0,1024)
                int q = u >> 4, part = u & 15;   // 16 int4-groups per q-row
                int4 mv = *(const int4*)(Mp + (long)q * 2048 + kt * 64 + part * 4);
                uchar4 mo;
                mo.x = (unsigned char)mv.x; mo.y = (unsigned char)mv.y;
                mo.z = (unsigned char)mv.z; mo.w = (unsigned char)mv.w;
                *(uchar4*)&Ms[q * 64 + part * 4] = mo;
            }
        }
        __syncthreads();

        // S = Q K^T  (wave owns q rows [wave*16, wave*16+16), all 64 keys)
        f32x4 S[4] = {};
#pragma unroll
        for (int ks = 0; ks < 2; ks++) {
            v8bf aq = *(const v8bf*)&Qs[(wave * 16 + lcol) * LDT + ks * 32 + lq * 8];
#pragma unroll
            for (int nt = 0; nt < 4; nt++) {
                v8bf bk = *(const v8bf*)&Ks[(nt * 16 + lcol) * LDT + ks * 32 + lq * 8];
                S[nt] = __builtin_amdgcn_mfma_f32_16x16x32_bf16(aq, bk, S[nt], 0, 0, 0);
            }
        }
        // scale + mask (C-layout: row = lq*4+r, col = nt*16+lcol)
        float p[4][4];
#pragma unroll
        for (int nt = 0; nt < 4; nt++)
#pragma unroll
            for (int r = 0; r < 4; r++) {
                float s = S[nt][r] * 0.125f;
                if (Ms[(wave * 16 + lq * 4 + r) * 64 + nt * 16 + lcol]) s = -1e30f;
                p[nt][r] = s;
            }
        // online softmax (4 rows per lane, replicated over 16-lane groups)
        float mnew[4], alpha[4];
#pragma unroll
        for (int r = 0; r < 4; r++) {
            float mx = fmaxf(fmaxf(p[0][r], p[1][r]), fmaxf(p[2][r], p[3][r]));
            mx = fmaxf(mx, __shfl_xor(mx, 1));
            mx = fmaxf(mx, __shfl_xor(mx, 2));
            mx = fmaxf(mx, __shfl_xor(mx, 4));
            mx = fmaxf(mx, __shfl_xor(mx, 8));
            mnew[r] = fmaxf(mrow[r], mx);
            alpha[r] = __expf(mrow[r] - mnew[r]);
            mrow[r] = mnew[r];
        }
#pragma unroll
        for (int r = 0; r < 4; r++) {
            float sum = 0.f;
#pragma unroll
            for (int nt = 0; nt < 4; nt++) {
                float e = __expf(p[nt][r] - mnew[r]);
                p[nt][r] = e;
                sum += e;
            }
            sum += __shfl_xor(sum, 1);
            sum += __shfl_xor(sum, 2);
            sum += __shfl_xor(sum, 4);
            sum += __shfl_xor(sum, 8);
            lsum[r] = lsum[r] * alpha[r] + sum;
#pragma unroll
            for (int nt = 0; nt < 4; nt++) Oacc[nt][r] *= alpha[r];
        }
        // P: C-layout -> LDS (row-major [16][64] padded) for A-operand reload
#pragma unroll
        for (int nt = 0; nt < 4; nt++)
#pragma unroll
            for (int r = 0; r < 4; r++)
                Ps[wave][(lq * 4 + r) * LDT + nt * 16 + lcol] = __float2bfloat16(p[nt][r]);
        __syncthreads();

        // O += P @ V   (A = P [16 q][64 key], B = V [64 key][64 dh] via Vts)
#pragma unroll
        for (int ks = 0; ks < 2; ks++) {
            v8bf ap = *(const v8bf*)&Ps[wave][lcol * LDT + ks * 32 + lq * 8];
#pragma unroll
            for (int nt = 0; nt < 4; nt++) {
                v8bf bv = *(const v8bf*)&Vts[(nt * 16 + lcol) * LDT + ks * 32 + lq * 8];
                Oacc[nt] = __builtin_amdgcn_mfma_f32_16x16x32_bf16(ap, bv, Oacc[nt], 0, 0, 0);
            }
        }
        __syncthreads();
    }

    // epilogue: y[b, q, h*64+dh] bf16 (head-interleaved for the final GEMM)
#pragma unroll
    for (int r = 0; r < 4; r++) {
        float inv = 1.f / lsum[r];
#pragma unroll
        for (int nt = 0; nt < 4; nt++) {
            long row = (long)b * 1024 + qt * 64 + wave * 16 + lq * 4 + r;
            int col = h * 64 + nt * 16 + lcol;
            Y[row * 512 + col] = __float2bfloat16(Oacc[nt][r] * inv);
        }
    }
}

// ---- launch -------------------------------------------------------------
extern "C" void kernel_launch(void* const* d_in, const int* in_sizes, int n_in,
                              void* d_out, int out_size, void* d_ws, size_t ws_size,
                              hipStream_t stream) {
    const float* x = (const float*)d_in[0];
    const float* c = (const float*)d_in[1];
    const int* mask = (const int*)d_in[2];
    const float* Wq = (const float*)d_in[3];
    const float* Wk = (const float*)d_in[4];
    const float* Wv = (const float*)d_in[5];
    const float* Wp = (const float*)d_in[6];

    char* ws = (char*)d_ws;
    __hip_bfloat16* xc  = (__hip_bfloat16*)(ws);                 // 16,777,216 B
    __hip_bfloat16* Wbf = (__hip_bfloat16*)(ws + 16777216);      //  2,097,152 B
    __hip_bfloat16* Qw  = (__hip_bfloat16*)(ws + 18874368);      //  8,388,608 B
    __hip_bfloat16* Kw  = (__hip_bfloat16*)(ws + 27262976);      // 16,777,216 B
    __hip_bfloat16* Vtw = (__hip_bfloat16*)(ws + 44040192);      // 16,777,216 B
    __hip_bfloat16* Yb  = (__hip_bfloat16*)(ws + 60817408);      //  8,388,608 B

    cvt_xc<<<8192, 256, 0, stream>>>(x, c, xc);
    cvt_w<<<1024, 256, 0, stream>>>(Wq, Wk, Wv, Wp, Wbf);
    // Q: M=8192 (x rows only: row -> (r/1024)*2048 + r%1024), out [B,H,1024,64]
    gemm_bt<0><<<dim3(64, 4), 256, 0, stream>>>(xc, Wbf, Qw, 1024, 2048, 1024);
    // K: M=16384, out [B,H,2048,64]
    gemm_bt<0><<<dim3(128, 4), 256, 0, stream>>>(xc, Wbf + 262144, Kw, 2048, 2048, 2048);
    // V: M=16384, out transposed [B,H,64,2048]
    gemm_bt<1><<<dim3(128, 4), 256, 0, stream>>>(xc, Wbf + 2 * 262144, Vtw, 2048, 2048, 2048);
    // attention
    flash<<<dim3(16, 64), 256, 0, stream>>>(Qw, Kw, Vtw, mask, Yb);
    // output projection -> fp32 d_out
    gemm_bt<2><<<dim3(64, 4), 256, 0, stream>>>(Yb, Wbf + 3 * 262144, d_out, 8192, 8192, 8192);
}